// Round 5
// baseline (13661.473 us; speedup 1.0000x reference)
//
#include <hip/hip_runtime.h>
#include <hip/hip_bf16.h>
#include <hip/hip_fp16.h>
#include <stdint.h>

#define BB  256
#define TT  512
#define FF  8
#define HH  256
#define H4  1024
#define DEC 35
#define NWG 16
#define MW  16

typedef __attribute__((ext_vector_type(8))) short short8v;
typedef __attribute__((ext_vector_type(4))) float f32x4;

// dynamic-LDS layout (bytes)
#define OFF_LDSW 0              // 16 slots * 8 kc * 64 lanes * 16B = 131072
#define OFF_HHI  131072         // h hi A-frags: 8 kc * 64 * 16B = 8192
#define OFF_HLO  139264         // h lo A-frags: 8192
#define OFF_MLP  147456         // sWmlp 512 f32 = 2048
#define OFF_SM   149504         // 6 f32 + pad = 32
#define SMEM_TOT 149536

__device__ __forceinline__ unsigned short f2bf(float x) {
    unsigned u = __float_as_uint(x);
    u += 0x7fffu + ((u >> 16) & 1u);          // RNE
    return (unsigned short)(u >> 16);
}
__device__ __forceinline__ float bf2f(unsigned s) { return __uint_as_float(s << 16); }
__device__ __forceinline__ float2 h2tof2(unsigned u) {
    __half2 h2 = *reinterpret_cast<const __half2*>(&u);
    return __half22float2(h2);
}
__device__ __forceinline__ float sigf(float x) {
    x = fminf(fmaxf(x, -30.f), 30.f);
    return 1.0f / (1.0f + __expf(-x));
}
__device__ __forceinline__ float tanh_(float x) {
    x = fminf(fmaxf(x, -15.f), 15.f);
    float e = __expf(2.0f * x);
    return (e - 1.0f) / (e + 1.0f);
}

// ===================== prep kernels =====================

// wpxh[n][f] = f16( bnscale[f] * (W_pe @ W_x)[f][n] )   (16B per n -> one uint4)
// zbias[n]  = b_lstm + b_pe@W_x + bnshift@(W_pe@W_x)
// zdec0[n]  = b_lstm + embed@W_x
__global__ void prep_consts(const float* __restrict__ W_pe, const float* __restrict__ b_pe,
                            const float* __restrict__ embed, const float* __restrict__ W_x,
                            const float* __restrict__ b_lstm,
                            const float* __restrict__ bn_gamma, const float* __restrict__ bn_beta,
                            const float* __restrict__ bn_mean, const float* __restrict__ bn_var,
                            __half* __restrict__ wpxh, float* __restrict__ zbias,
                            float* __restrict__ zdec0) {
    int n = blockIdx.x * 256 + threadIdx.x;
    float acc[FF];
    #pragma unroll
    for (int f = 0; f < FF; ++f) acc[f] = 0.f;
    float bsum = 0.f, dsum = 0.f;
    for (int m = 0; m < HH; ++m) {
        float wx = W_x[m * H4 + n];
        #pragma unroll
        for (int f = 0; f < FF; ++f) acc[f] = fmaf(W_pe[f * HH + m], wx, acc[f]);
        bsum = fmaf(b_pe[m], wx, bsum);
        dsum = fmaf(embed[m], wx, dsum);
    }
    float zb = b_lstm[n] + bsum;
    #pragma unroll
    for (int f = 0; f < FF; ++f) {
        float s  = bn_gamma[f] * rsqrtf(bn_var[f] + 1e-3f);
        float sh = bn_beta[f] - bn_mean[f] * s;
        wpxh[n * FF + f] = __float2half(s * acc[f]);
        zb = fmaf(sh, acc[f], zb);
    }
    zbias[n] = zb;
    zdec0[n] = b_lstm[n] + dsum;
}

// B-frags: frag[(nt*8+kc)*64+ln][j] = W[k = kc*32 + 8*(ln>>4) + j][nt*16 + (ln&15)]
__global__ void prep_wfrag(const float* __restrict__ W_x, const float* __restrict__ W_h,
                           short8v* __restrict__ whf, short8v* __restrict__ wsf) {
    int nt = blockIdx.x >> 3, kc = blockIdx.x & 7, ln = threadIdx.x;
    int n = nt * 16 + (ln & 15), q = ln >> 4;
    short8v vh, vs;
    #pragma unroll
    for (int j = 0; j < 8; ++j) {
        int k = kc * 32 + q * 8 + j;
        float wh = W_h[k * H4 + n], wx = W_x[k * H4 + n];
        vh[j] = (short)f2bf(wh);
        vs[j] = (short)f2bf(wx + wh);
    }
    whf[blockIdx.x * 64 + ln] = vh;
    wsf[blockIdx.x * 64 + ln] = vs;
}

// ===================== main recurrent kernel =====================
// 16 WGs x 512 thr, batch-group of 16 per WG. Wave w owns col-tiles
// nt = (tl>>1)*16 + 2w + (tl&1)  (all 4 gates of units [32w,32w+32)).
// Gate f tiles (tl=2,3) LDS-resident; others streamed from L2.
// h kept as SPLIT bf16 (hi+lo) A-frags -> ~fp32-equivalent recurrence.
// zx (input projection, K=8) computed scalar fp32 per lane.
__global__ __launch_bounds__(512, 2) void lstm_rec3(
    const short8v* __restrict__ whf, const short8v* __restrict__ wsf,
    const uint4* __restrict__ wpx4,
    const float* __restrict__ pulse,
    const float* __restrict__ zbias, const float* __restrict__ zdec0,
    const float* __restrict__ blstm,
    const float* __restrict__ W_mlp, const float* __restrict__ b_mlp,
    const float* __restrict__ scale_w, const float* __restrict__ scale_b,
    float* __restrict__ out) {
    extern __shared__ char smem[];
    short8v* ldsW  = (short8v*)(smem + OFF_LDSW);
    short8v* ldsHI = (short8v*)(smem + OFF_HHI);
    short8v* ldsLO = (short8v*)(smem + OFF_HLO);
    unsigned short* hHIs = (unsigned short*)(smem + OFF_HHI);
    unsigned short* hLOs = (unsigned short*)(smem + OFF_HLO);
    float*   sWmlp = (float*)(smem + OFF_MLP);
    float*   sm    = (float*)(smem + OFF_SM);

    const int tid = threadIdx.x, g = blockIdx.x;
    const int w = tid >> 6, ln = tid & 63;
    const int col = ln & 15, q = ln >> 4;

    int ntv[8];
    #pragma unroll
    for (int tl = 0; tl < 8; ++tl) ntv[tl] = (tl >> 1) * 16 + 2 * w + (tl & 1);

    // ---- init ----
    #pragma unroll
    for (int tl = 2; tl < 4; ++tl) {
        int slot = w * 2 + (tl - 2);
        #pragma unroll
        for (int kc = 0; kc < 8; ++kc)
            ldsW[(slot * 8 + kc) * 64 + ln] = whf[(ntv[tl] * 8 + kc) * 64 + ln];
    }
    {
        short8v zz = {};
        for (int i = tid; i < 8 * 64; i += 512) { ldsHI[i] = zz; ldsLO[i] = zz; }
    }
    for (int i = tid; i < HH * 2; i += 512) sWmlp[i] = W_mlp[i];
    if (tid < 2) { sm[tid] = b_mlp[tid]; sm[2 + tid] = scale_w[tid]; sm[4 + tid] = scale_b[tid]; }

    // per-lane Wpx (f16, 8 tiles x 8 f = 32 VGPR) and biases
    uint4 wpx[8];
    float zb[8];
    #pragma unroll
    for (int tl = 0; tl < 8; ++tl) {
        int n = ntv[tl] * 16 + col;
        wpx[tl] = wpx4[n];
        zb[tl]  = zbias[n];
    }

    float c[8];
    #pragma unroll
    for (int i = 0; i < 8; ++i) c[i] = 0.f;

    const int hwo = w * 512;   // this wave's kc block (shorts) in h-frag buffers
    const float* pbase = pulse + (size_t)(g * MW) * TT * FF;

    // x prefetch registers for t=0 (rows 4q+r, raw pulse, 8 floats each)
    float4 xr[4][2];
    #pragma unroll
    for (int r = 0; r < 4; ++r) {
        const float* pr = pbase + (size_t)(4 * q + r) * TT * FF;
        xr[r][0] = ((const float4*)pr)[0];
        xr[r][1] = ((const float4*)pr)[1];
    }
    __syncthreads();

    // ---- encoder: 512 steps ----
    for (int t = 0; t < TT; ++t) {
        short8v ahi[8], alo[8];
        #pragma unroll
        for (int kc = 0; kc < 8; ++kc) {
            ahi[kc] = ldsHI[kc * 64 + ln];
            alo[kc] = ldsLO[kc * 64 + ln];
        }
        float4 xc[4][2];
        #pragma unroll
        for (int r = 0; r < 4; ++r) { xc[r][0] = xr[r][0]; xc[r][1] = xr[r][1]; }
        {   // prefetch next step's pulse rows
            int tn = (t + 1 < TT) ? t + 1 : TT - 1;
            #pragma unroll
            for (int r = 0; r < 4; ++r) {
                const float* pr = pbase + (size_t)(4 * q + r) * TT * FF + (size_t)tn * FF;
                xr[r][0] = ((const float4*)pr)[0];
                xr[r][1] = ((const float4*)pr)[1];
            }
        }
        __syncthreads();   // frag reads done before overwrites

        f32x4 acc[8];
        // zx init: fp32 scalar, Wpx f16 -> f32
        #pragma unroll
        for (int tl = 0; tl < 8; ++tl) {
            float wv[8];
            float2 d;
            d = h2tof2(wpx[tl].x); wv[0] = d.x; wv[1] = d.y;
            d = h2tof2(wpx[tl].y); wv[2] = d.x; wv[3] = d.y;
            d = h2tof2(wpx[tl].z); wv[4] = d.x; wv[5] = d.y;
            d = h2tof2(wpx[tl].w); wv[6] = d.x; wv[7] = d.y;
            f32x4 av;
            #pragma unroll
            for (int r = 0; r < 4; ++r) {
                float s = zb[tl];
                s = fmaf(xc[r][0].x, wv[0], s); s = fmaf(xc[r][0].y, wv[1], s);
                s = fmaf(xc[r][0].z, wv[2], s); s = fmaf(xc[r][0].w, wv[3], s);
                s = fmaf(xc[r][1].x, wv[4], s); s = fmaf(xc[r][1].y, wv[5], s);
                s = fmaf(xc[r][1].z, wv[6], s); s = fmaf(xc[r][1].w, wv[7], s);
                av[r] = s;
            }
            acc[tl] = av;
        }
        // streamed tiles (gates i,g,o)
        #pragma unroll
        for (int tl = 0; tl < 8; ++tl) {
            if (tl == 2 || tl == 3) continue;
            const short8v* wp = whf + (size_t)(ntv[tl] * 8) * 64 + ln;
            f32x4 av = acc[tl];
            #pragma unroll
            for (int kc = 0; kc < 8; ++kc) {
                short8v b = wp[kc * 64];
                av = __builtin_amdgcn_mfma_f32_16x16x32_bf16(ahi[kc], b, av, 0, 0, 0);
                av = __builtin_amdgcn_mfma_f32_16x16x32_bf16(alo[kc], b, av, 0, 0, 0);
            }
            acc[tl] = av;
        }
        // LDS tiles (gate f)
        #pragma unroll
        for (int tl = 2; tl < 4; ++tl) {
            int slot = w * 2 + (tl - 2);
            f32x4 av = acc[tl];
            #pragma unroll
            for (int kc = 0; kc < 8; ++kc) {
                short8v b = ldsW[(slot * 8 + kc) * 64 + ln];
                av = __builtin_amdgcn_mfma_f32_16x16x32_bf16(ahi[kc], b, av, 0, 0, 0);
                av = __builtin_amdgcn_mfma_f32_16x16x32_bf16(alo[kc], b, av, 0, 0, 0);
            }
            acc[tl] = av;
        }

        // gate math + split-h write
        #pragma unroll
        for (int p = 0; p < 2; ++p)
            #pragma unroll
            for (int r = 0; r < 4; ++r) {
                float cc = sigf(acc[2 + p][r]) * c[p * 4 + r] + sigf(acc[p][r]) * tanh_(acc[4 + p][r]);
                c[p * 4 + r] = cc;
                float hh = sigf(acc[6 + p][r]) * tanh_(cc);
                unsigned short hi = f2bf(hh);
                float lo = hh - bf2f(hi);
                int ad = hwo + (2 * p + (col >> 3)) * 128 + (4 * q + r) * 8 + (col & 7);
                hHIs[ad] = hi;
                hLOs[ad] = f2bf(lo);
            }
        __syncthreads();
    }

    // ---- decoder: 35 steps ----
    float zd0[8], bl[8];
    #pragma unroll
    for (int tl = 0; tl < 8; ++tl) {
        zd0[tl] = zdec0[ntv[tl] * 16 + col];
        bl[tl]  = blstm[ntv[tl] * 16 + col];
    }

    for (int s = 0; s < DEC; ++s) {
        short8v ahi[8], alo[8];
        #pragma unroll
        for (int kc = 0; kc < 8; ++kc) {
            ahi[kc] = ldsHI[kc * 64 + ln];
            alo[kc] = ldsLO[kc * 64 + ln];
        }
        __syncthreads();

        f32x4 acc[8];
        if (s == 0) {
            // z = zdec0 + h@W_h
            #pragma unroll
            for (int tl = 0; tl < 8; ++tl) {
                f32x4 av; av[0] = zd0[tl]; av[1] = zd0[tl]; av[2] = zd0[tl]; av[3] = zd0[tl];
                if (tl == 2 || tl == 3) {
                    int slot = w * 2 + (tl - 2);
                    #pragma unroll
                    for (int kc = 0; kc < 8; ++kc) {
                        short8v b = ldsW[(slot * 8 + kc) * 64 + ln];
                        av = __builtin_amdgcn_mfma_f32_16x16x32_bf16(ahi[kc], b, av, 0, 0, 0);
                        av = __builtin_amdgcn_mfma_f32_16x16x32_bf16(alo[kc], b, av, 0, 0, 0);
                    }
                } else {
                    const short8v* wp = whf + (size_t)(ntv[tl] * 8) * 64 + ln;
                    #pragma unroll
                    for (int kc = 0; kc < 8; ++kc) {
                        short8v b = wp[kc * 64];
                        av = __builtin_amdgcn_mfma_f32_16x16x32_bf16(ahi[kc], b, av, 0, 0, 0);
                        av = __builtin_amdgcn_mfma_f32_16x16x32_bf16(alo[kc], b, av, 0, 0, 0);
                    }
                }
                acc[tl] = av;
            }
        } else {
            // z = b_lstm + h@(W_x+W_h)  (W_sum streamed)
            #pragma unroll
            for (int tl = 0; tl < 8; ++tl) {
                f32x4 av; av[0] = bl[tl]; av[1] = bl[tl]; av[2] = bl[tl]; av[3] = bl[tl];
                const short8v* wp = wsf + (size_t)(ntv[tl] * 8) * 64 + ln;
                #pragma unroll
                for (int kc = 0; kc < 8; ++kc) {
                    short8v b = wp[kc * 64];
                    av = __builtin_amdgcn_mfma_f32_16x16x32_bf16(ahi[kc], b, av, 0, 0, 0);
                    av = __builtin_amdgcn_mfma_f32_16x16x32_bf16(alo[kc], b, av, 0, 0, 0);
                }
                acc[tl] = av;
            }
        }

        #pragma unroll
        for (int p = 0; p < 2; ++p)
            #pragma unroll
            for (int r = 0; r < 4; ++r) {
                float cc = sigf(acc[2 + p][r]) * c[p * 4 + r] + sigf(acc[p][r]) * tanh_(acc[4 + p][r]);
                c[p * 4 + r] = cc;
                float hh = sigf(acc[6 + p][r]) * tanh_(cc);
                unsigned short hi = f2bf(hh);
                float lo = hh - bf2f(hi);
                int ad = hwo + (2 * p + (col >> 3)) * 128 + (4 * q + r) * 8 + (col & 7);
                hHIs[ad] = hi;
                hLOs[ad] = f2bf(lo);
            }
        __syncthreads();

        // MLP head from split-h frags: h[m][u], addr(u,m) = (u>>5)*512 + ((u>>3)&3)*128 + m*8 + (u&7)
        {
            int m = tid >> 5, j = (tid >> 4) & 1, uc = tid & 15;
            float p2 = 0.f;
            #pragma unroll
            for (int i = 0; i < 16; ++i) {
                int u = i * 16 + uc;
                int ad = (u >> 5) * 512 + ((u >> 3) & 3) * 128 + m * 8 + (u & 7);
                float hv = bf2f(hHIs[ad]) + bf2f(hLOs[ad]);
                p2 = fmaf(hv, sWmlp[u * 2 + j], p2);
            }
            p2 += __shfl_down(p2, 8, 16);
            p2 += __shfl_down(p2, 4, 16);
            p2 += __shfl_down(p2, 2, 16);
            p2 += __shfl_down(p2, 1, 16);
            if (uc == 0) {
                float pr = p2 + sm[j];
                out[((size_t)(g * MW + m) * DEC + s) * 2 + j] = pr * sm[2 + j] + sm[4 + j];
            }
        }
        __syncthreads();
    }
}

// ===================== fallback (round-2, proven) =====================
__global__ void prep_weights(const float* __restrict__ Wx, const float* __restrict__ Wh,
                             __hip_bfloat16* __restrict__ wxb,
                             __hip_bfloat16* __restrict__ whb,
                             __hip_bfloat16* __restrict__ wsb) {
    int i = blockIdx.x * 256 + threadIdx.x;
    if (i < HH * H4) {
        float x = Wx[i], h = Wh[i];
        wxb[i] = __float2bfloat16(x);
        whb[i] = __float2bfloat16(h);
        wsb[i] = __float2bfloat16(x + h);
    }
}

template<bool BF16W>
__device__ __forceinline__ void matvec2(const void* __restrict__ W,
                                        const float* __restrict__ vec,
                                        int tid, float& z0, float& z1) {
    if constexpr (BF16W) {
        const uint32_t* Wp = (const uint32_t*)W;
        #pragma unroll 8
        for (int k = 0; k < HH; ++k) {
            uint32_t w = Wp[(size_t)k * (H4 / 2) + tid];
            float s = vec[k];
            union { uint32_t u; float f; } lo, hi;
            lo.u = w << 16;
            hi.u = w & 0xffff0000u;
            z0 = fmaf(s, lo.f, z0);
            z1 = fmaf(s, hi.f, z1);
        }
    } else {
        const float2* Wp = (const float2*)W;
        #pragma unroll 8
        for (int k = 0; k < HH; ++k) {
            float2 w = Wp[(size_t)k * (H4 / 2) + tid];
            float s = vec[k];
            z0 = fmaf(s, w.x, z0);
            z1 = fmaf(s, w.y, z1);
        }
    }
}

__device__ __forceinline__ float sigmoidf_(float x) { return 1.0f / (1.0f + expf(-x)); }

template<bool BF16W>
__global__ __launch_bounds__(512)
void lstm_persist(const float* __restrict__ pulse,
                  const float* __restrict__ bn_gamma, const float* __restrict__ bn_beta,
                  const float* __restrict__ bn_mean, const float* __restrict__ bn_var,
                  const float* __restrict__ W_pe, const float* __restrict__ b_pe,
                  const float* __restrict__ embed,
                  const float* __restrict__ W_x, const float* __restrict__ W_h,
                  const float* __restrict__ b_lstm,
                  const float* __restrict__ W_mlp, const float* __restrict__ b_mlp,
                  const float* __restrict__ scale_w, const float* __restrict__ scale_b,
                  const void* __restrict__ WxQ, const void* __restrict__ WhQ,
                  const void* __restrict__ WsQ,
                  float* __restrict__ out) {
    __shared__ float sWpe2[FF * HH];
    __shared__ float sbpe2[HH];
    __shared__ float sbl[H4];
    __shared__ float sWmlp[HH * 2];
    __shared__ float sbuf[HH];
    __shared__ float hbuf[HH];
    __shared__ float cbuf[HH];
    __shared__ float zbuf[H4];
    __shared__ float bnsc[FF], bnsh[FF];
    __shared__ float smisc[6];

    const int tid = threadIdx.x;
    const int bb  = blockIdx.x;

    if (tid < FF) {
        float s = bn_gamma[tid] * rsqrtf(bn_var[tid] + 1e-3f);
        bnsc[tid] = s;
        bnsh[tid] = bn_beta[tid] - bn_mean[tid] * s;
    }
    if (tid < 2) {
        smisc[tid]     = b_mlp[tid];
        smisc[2 + tid] = scale_w[tid];
        smisc[4 + tid] = scale_b[tid];
    }
    for (int i = tid; i < H4; i += 512) sbl[i] = b_lstm[i];
    for (int i = tid; i < 2 * HH; i += 512) sWmlp[i] = W_mlp[i];
    for (int i = tid; i < HH; i += 512) { hbuf[i] = 0.f; cbuf[i] = 0.f; }
    __syncthreads();
    for (int i = tid; i < FF * HH; i += 512) sWpe2[i] = W_pe[i] * bnsc[i / HH];
    for (int i = tid; i < HH; i += 512) {
        float a = b_pe[i];
        #pragma unroll
        for (int f = 0; f < FF; ++f) a = fmaf(bnsh[f], W_pe[f * HH + i], a);
        sbpe2[i] = a;
    }
    __syncthreads();
    if (tid >= HH && tid < 2 * HH) {
        int u = tid - HH;
        const float* pr = pulse + (size_t)bb * TT * FF;
        float acc = sbpe2[u];
        #pragma unroll
        for (int f = 0; f < FF; ++f) acc = fmaf(pr[f], sWpe2[f * HH + u], acc);
        sbuf[u] = acc;
    }
    __syncthreads();

    for (int t = 0; t < TT; ++t) {
        float z0 = sbl[2 * tid], z1 = sbl[2 * tid + 1];
        if constexpr (BF16W) {
            matvec2<true>(WxQ, sbuf, tid, z0, z1);
            matvec2<true>(WhQ, hbuf, tid, z0, z1);
        } else {
            matvec2<false>(W_x, sbuf, tid, z0, z1);
            matvec2<false>(W_h, hbuf, tid, z0, z1);
        }
        zbuf[2 * tid] = z0; zbuf[2 * tid + 1] = z1;
        __syncthreads();
        if (tid < HH) {
            float iv = zbuf[tid], fv = zbuf[tid + HH];
            float gv = zbuf[tid + 2 * HH], ov = zbuf[tid + 3 * HH];
            float c = sigmoidf_(fv) * cbuf[tid] + sigmoidf_(iv) * tanhf(gv);
            cbuf[tid] = c;
            hbuf[tid] = sigmoidf_(ov) * tanhf(c);
        } else if (tid < 2 * HH) {
            int u = tid - HH;
            float acc;
            if (t + 1 < TT) {
                const float* pr = pulse + ((size_t)bb * TT + (t + 1)) * FF;
                acc = sbpe2[u];
                #pragma unroll
                for (int f = 0; f < FF; ++f) acc = fmaf(pr[f], sWpe2[f * HH + u], acc);
            } else {
                acc = embed[u];
            }
            sbuf[u] = acc;
        }
        __syncthreads();
    }

    for (int s = 0; s < DEC; ++s) {
        float z0 = sbl[2 * tid], z1 = sbl[2 * tid + 1];
        if (s == 0) {
            if constexpr (BF16W) {
                matvec2<true>(WxQ, sbuf, tid, z0, z1);
                matvec2<true>(WhQ, hbuf, tid, z0, z1);
            } else {
                matvec2<false>(W_x, sbuf, tid, z0, z1);
                matvec2<false>(W_h, hbuf, tid, z0, z1);
            }
        } else {
            if constexpr (BF16W) {
                matvec2<true>(WsQ, hbuf, tid, z0, z1);
            } else {
                matvec2<false>(W_x, hbuf, tid, z0, z1);
                matvec2<false>(W_h, hbuf, tid, z0, z1);
            }
        }
        zbuf[2 * tid] = z0; zbuf[2 * tid + 1] = z1;
        __syncthreads();
        if (tid < HH) {
            float iv = zbuf[tid], fv = zbuf[tid + HH];
            float gv = zbuf[tid + 2 * HH], ov = zbuf[tid + 3 * HH];
            float c = sigmoidf_(fv) * cbuf[tid] + sigmoidf_(iv) * tanhf(gv);
            cbuf[tid] = c;
            hbuf[tid] = sigmoidf_(ov) * tanhf(c);
        }
        __syncthreads();
        if (tid < 128) {
            int j = tid >> 6, lane = tid & 63;
            float p = 0.f;
            #pragma unroll
            for (int u = lane; u < HH; u += 64) p = fmaf(hbuf[u], sWmlp[u * 2 + j], p);
            p += __shfl_down(p, 32); p += __shfl_down(p, 16); p += __shfl_down(p, 8);
            p += __shfl_down(p, 4);  p += __shfl_down(p, 2);  p += __shfl_down(p, 1);
            if (lane == 0) {
                float pr2 = p + smisc[j];
                out[((size_t)bb * DEC + s) * 2 + j] = pr2 * smisc[2 + j] + smisc[4 + j];
            }
        }
        __syncthreads();
    }
}

extern "C" void kernel_launch(void* const* d_in, const int* in_sizes, int n_in,
                              void* d_out, int out_size, void* d_ws, size_t ws_size,
                              hipStream_t stream) {
    const float* pulse    = (const float*)d_in[0];
    const float* bn_gamma = (const float*)d_in[1];
    const float* bn_beta  = (const float*)d_in[2];
    const float* bn_mean  = (const float*)d_in[3];
    const float* bn_var   = (const float*)d_in[4];
    const float* W_pe     = (const float*)d_in[5];
    const float* b_pe     = (const float*)d_in[6];
    const float* embed    = (const float*)d_in[7];
    const float* W_x      = (const float*)d_in[8];
    const float* W_h      = (const float*)d_in[9];
    const float* b_lstm   = (const float*)d_in[10];
    const float* W_mlp    = (const float*)d_in[11];
    const float* b_mlp    = (const float*)d_in[12];
    const float* scale_w  = (const float*)d_in[13];
    const float* scale_b  = (const float*)d_in[14];
    float* out = (float*)d_out;

    // ws layout: whf 512K | wsf 512K | wpxh 16K | zbias 4K | zdec0 4K
    const size_t SZ_WF  = (size_t)64 * 8 * 64 * 16;     // 524288
    const size_t SZ_PXH = (size_t)H4 * FF * 2;          // 16384
    const size_t needA = 2 * SZ_WF + SZ_PXH + 2 * (size_t)H4 * 4;

    if (ws_size >= needA) {
        short8v* whf   = (short8v*)d_ws;
        short8v* wsf   = (short8v*)((char*)d_ws + SZ_WF);
        __half*  wpxh  = (__half*)((char*)d_ws + 2 * SZ_WF);
        float*   zbias = (float*)((char*)d_ws + 2 * SZ_WF + SZ_PXH);
        float*   zdec0 = zbias + H4;

        hipFuncSetAttribute((const void*)lstm_rec3,
                            hipFuncAttributeMaxDynamicSharedMemorySize, SMEM_TOT);

        prep_consts<<<4, 256, 0, stream>>>(W_pe, b_pe, embed, W_x, b_lstm,
                                           bn_gamma, bn_beta, bn_mean, bn_var,
                                           wpxh, zbias, zdec0);
        prep_wfrag<<<512, 64, 0, stream>>>(W_x, W_h, whf, wsf);
        lstm_rec3<<<NWG, 512, SMEM_TOT, stream>>>(whf, wsf, (const uint4*)wpxh, pulse,
                                                  zbias, zdec0, b_lstm,
                                                  W_mlp, b_mlp, scale_w, scale_b, out);
        return;
    }

    const size_t NW = (size_t)HH * H4;
    bool use_bf16 = ws_size >= 3 * NW * sizeof(__hip_bfloat16);
    __hip_bfloat16* wxb = (__hip_bfloat16*)d_ws;
    __hip_bfloat16* whb = wxb + NW;
    __hip_bfloat16* wsb = whb + NW;

    if (use_bf16) {
        prep_weights<<<(int)((NW + 255) / 256), 256, 0, stream>>>(W_x, W_h, wxb, whb, wsb);
        lstm_persist<true><<<BB, 512, 0, stream>>>(
            pulse, bn_gamma, bn_beta, bn_mean, bn_var, W_pe, b_pe, embed,
            W_x, W_h, b_lstm, W_mlp, b_mlp, scale_w, scale_b,
            (const void*)wxb, (const void*)whb, (const void*)wsb, out);
    } else {
        lstm_persist<false><<<BB, 512, 0, stream>>>(
            pulse, bn_gamma, bn_beta, bn_mean, bn_var, W_pe, b_pe, embed,
            W_x, W_h, b_lstm, W_mlp, b_mlp, scale_w, scale_b,
            nullptr, nullptr, nullptr, out);
    }
}

// Round 6
// 8828.848 us; speedup vs baseline: 1.5474x; 1.5474x over previous
//
#include <hip/hip_runtime.h>
#include <hip/hip_bf16.h>
#include <hip/hip_fp16.h>
#include <stdint.h>

#define BB  256
#define TT  512
#define FF  8
#define HH  256
#define H4  1024
#define DEC 35
#define NWG 16
#define MW  16

typedef __attribute__((ext_vector_type(8))) short short8v;
typedef __attribute__((ext_vector_type(4))) float f32x4;

// dynamic-LDS layout (bytes)
#define OFF_LDSW 0              // 16 slots * 8 kc * 64 lanes * 16B = 131072
#define OFF_HHI  131072         // h hi A-frags: 8 kc * 64 * 16B = 8192
#define OFF_HLO  139264         // h lo A-frags: 8192
#define OFF_MLP  147456         // sWmlp 512 f32 = 2048
#define OFF_SM   149504         // 6 f32 + pad = 32
#define SMEM_TOT 149536

__device__ __forceinline__ unsigned short f2bf(float x) {
    unsigned u = __float_as_uint(x);
    u += 0x7fffu + ((u >> 16) & 1u);          // RNE
    return (unsigned short)(u >> 16);
}
__device__ __forceinline__ float bf2f(unsigned s) { return __uint_as_float(s << 16); }
__device__ __forceinline__ float2 h2tof2(unsigned u) {
    __half2 h2 = *reinterpret_cast<const __half2*>(&u);
    return __half22float2(h2);
}
__device__ __forceinline__ float sigf(float x) {
    x = fminf(fmaxf(x, -30.f), 30.f);
    return 1.0f / (1.0f + __expf(-x));
}
__device__ __forceinline__ float tanh_(float x) {
    x = fminf(fmaxf(x, -15.f), 15.f);
    float e = __expf(2.0f * x);
    return (e - 1.0f) / (e + 1.0f);
}

// ===================== prep kernels =====================

__global__ void prep_consts(const float* __restrict__ W_pe, const float* __restrict__ b_pe,
                            const float* __restrict__ embed, const float* __restrict__ W_x,
                            const float* __restrict__ b_lstm,
                            const float* __restrict__ bn_gamma, const float* __restrict__ bn_beta,
                            const float* __restrict__ bn_mean, const float* __restrict__ bn_var,
                            __half* __restrict__ wpxh, float* __restrict__ zbias,
                            float* __restrict__ zdec0) {
    int n = blockIdx.x * 256 + threadIdx.x;
    float acc[FF];
    #pragma unroll
    for (int f = 0; f < FF; ++f) acc[f] = 0.f;
    float bsum = 0.f, dsum = 0.f;
    for (int m = 0; m < HH; ++m) {
        float wx = W_x[m * H4 + n];
        #pragma unroll
        for (int f = 0; f < FF; ++f) acc[f] = fmaf(W_pe[f * HH + m], wx, acc[f]);
        bsum = fmaf(b_pe[m], wx, bsum);
        dsum = fmaf(embed[m], wx, dsum);
    }
    float zb = b_lstm[n] + bsum;
    #pragma unroll
    for (int f = 0; f < FF; ++f) {
        float s  = bn_gamma[f] * rsqrtf(bn_var[f] + 1e-3f);
        float sh = bn_beta[f] - bn_mean[f] * s;
        wpxh[n * FF + f] = __float2half(s * acc[f]);
        zb = fmaf(sh, acc[f], zb);
    }
    zbias[n] = zb;
    zdec0[n] = b_lstm[n] + dsum;
}

// B-frags: frag[(nt*8+kc)*64+ln][j] = W[k = kc*32 + 8*(ln>>4) + j][nt*16 + (ln&15)]
__global__ void prep_wfrag(const float* __restrict__ W_x, const float* __restrict__ W_h,
                           short8v* __restrict__ whf, short8v* __restrict__ wsf) {
    int nt = blockIdx.x >> 3, kc = blockIdx.x & 7, ln = threadIdx.x;
    int n = nt * 16 + (ln & 15), q = ln >> 4;
    short8v vh, vs;
    #pragma unroll
    for (int j = 0; j < 8; ++j) {
        int k = kc * 32 + q * 8 + j;
        float wh = W_h[k * H4 + n], wx = W_x[k * H4 + n];
        vh[j] = (short)f2bf(wh);
        vs[j] = (short)f2bf(wx + wh);
    }
    whf[blockIdx.x * 64 + ln] = vh;
    wsf[blockIdx.x * 64 + ln] = vs;
}

// ===================== main recurrent kernel =====================
// 16 WGs x 512 thr, batch-group of 16 per WG. Wave w owns col-tiles
// nt = (tl>>1)*16 + 2w + (tl&1)  (all 4 gates of units [32w,32w+32)).
// Gate f tiles (tl=2,3) LDS-resident; others streamed (double-buffered prefetch).
// h kept SPLIT bf16 (hi+lo) -> ~fp32-equivalent recurrence. zx scalar fp32.
// __launch_bounds__(512,1): 256-VGPR cap (round 5's (512,2)=128 cap caused 18MB/launch spills)
__global__ __launch_bounds__(512, 1) void lstm_rec4(
    const short8v* __restrict__ whf, const short8v* __restrict__ wsf,
    const uint4* __restrict__ wpx4,
    const float* __restrict__ pulse,
    const float* __restrict__ zbias, const float* __restrict__ zdec0,
    const float* __restrict__ blstm,
    const float* __restrict__ W_mlp, const float* __restrict__ b_mlp,
    const float* __restrict__ scale_w, const float* __restrict__ scale_b,
    float* __restrict__ out) {
    extern __shared__ char smem[];
    short8v* ldsW  = (short8v*)(smem + OFF_LDSW);
    short8v* ldsHI = (short8v*)(smem + OFF_HHI);
    short8v* ldsLO = (short8v*)(smem + OFF_HLO);
    unsigned short* hHIs = (unsigned short*)(smem + OFF_HHI);
    unsigned short* hLOs = (unsigned short*)(smem + OFF_HLO);
    float*   sWmlp = (float*)(smem + OFF_MLP);
    float*   sm    = (float*)(smem + OFF_SM);

    const int tid = threadIdx.x, g = blockIdx.x;
    const int w = tid >> 6, ln = tid & 63;
    const int col = ln & 15, q = ln >> 4;

    int ntv[8];
    #pragma unroll
    for (int tl = 0; tl < 8; ++tl) ntv[tl] = (tl >> 1) * 16 + 2 * w + (tl & 1);

    // ---- init ----
    #pragma unroll
    for (int tl = 2; tl < 4; ++tl) {
        int slot = w * 2 + (tl - 2);
        #pragma unroll
        for (int kc = 0; kc < 8; ++kc)
            ldsW[(slot * 8 + kc) * 64 + ln] = whf[(ntv[tl] * 8 + kc) * 64 + ln];
    }
    {
        short8v zz = {};
        for (int i = tid; i < 8 * 64; i += 512) { ldsHI[i] = zz; ldsLO[i] = zz; }
    }
    for (int i = tid; i < HH * 2; i += 512) sWmlp[i] = W_mlp[i];
    if (tid < 2) { sm[tid] = b_mlp[tid]; sm[2 + tid] = scale_w[tid]; sm[4 + tid] = scale_b[tid]; }

    uint4 wpx[8];
    float zb[8];
    #pragma unroll
    for (int tl = 0; tl < 8; ++tl) {
        int n = ntv[tl] * 16 + col;
        wpx[tl] = wpx4[n];
        zb[tl]  = zbias[n];
    }

    float c[8];
    #pragma unroll
    for (int i = 0; i < 8; ++i) c[i] = 0.f;

    const int hwo = w * 512;
    const float* pbase = pulse + (size_t)(g * MW) * TT * FF;

    float4 xr[4][2];
    #pragma unroll
    for (int r = 0; r < 4; ++r) {
        const float* pr = pbase + (size_t)(4 * q + r) * TT * FF;
        xr[r][0] = ((const float4*)pr)[0];
        xr[r][1] = ((const float4*)pr)[1];
    }
    __syncthreads();

#define LOADW(dst, src, tl_) do {                                              \
        const short8v* wp_ = (src) + (size_t)(ntv[tl_] * 8) * 64 + ln;         \
        _Pragma("unroll")                                                      \
        for (int kc_ = 0; kc_ < 8; ++kc_) dst[kc_] = wp_[kc_ * 64];            \
    } while (0)

#define MFMA16(accv, buf) do {                                                 \
        _Pragma("unroll")                                                      \
        for (int kc_ = 0; kc_ < 8; ++kc_) {                                    \
            accv = __builtin_amdgcn_mfma_f32_16x16x32_bf16(ahi[kc_], buf[kc_], accv, 0, 0, 0); \
            accv = __builtin_amdgcn_mfma_f32_16x16x32_bf16(alo[kc_], buf[kc_], accv, 0, 0, 0); \
        }                                                                      \
    } while (0)

    // ---- encoder: 512 steps ----
    for (int t = 0; t < TT; ++t) {
        short8v ahi[8], alo[8];
        #pragma unroll
        for (int kc = 0; kc < 8; ++kc) {
            ahi[kc] = ldsHI[kc * 64 + ln];
            alo[kc] = ldsLO[kc * 64 + ln];
        }
        float4 xc[4][2];
        #pragma unroll
        for (int r = 0; r < 4; ++r) { xc[r][0] = xr[r][0]; xc[r][1] = xr[r][1]; }
        {
            int tn = (t + 1 < TT) ? t + 1 : TT - 1;
            #pragma unroll
            for (int r = 0; r < 4; ++r) {
                const float* pr = pbase + (size_t)(4 * q + r) * TT * FF + (size_t)tn * FF;
                xr[r][0] = ((const float4*)pr)[0];
                xr[r][1] = ((const float4*)pr)[1];
            }
        }
        __syncthreads();   // frag reads done before overwrites

        // start the weight stream (tiles 0,1) BEFORE the zx VALU work so the
        // first loads' latency hides under it
        short8v wA[8], wB[8];
        LOADW(wA, whf, 0);
        LOADW(wB, whf, 1);

        f32x4 acc[8];
        #pragma unroll
        for (int tl = 0; tl < 8; ++tl) {
            float wv[8];
            float2 d;
            d = h2tof2(wpx[tl].x); wv[0] = d.x; wv[1] = d.y;
            d = h2tof2(wpx[tl].y); wv[2] = d.x; wv[3] = d.y;
            d = h2tof2(wpx[tl].z); wv[4] = d.x; wv[5] = d.y;
            d = h2tof2(wpx[tl].w); wv[6] = d.x; wv[7] = d.y;
            f32x4 av;
            #pragma unroll
            for (int r = 0; r < 4; ++r) {
                float s = zb[tl];
                s = fmaf(xc[r][0].x, wv[0], s); s = fmaf(xc[r][0].y, wv[1], s);
                s = fmaf(xc[r][0].z, wv[2], s); s = fmaf(xc[r][0].w, wv[3], s);
                s = fmaf(xc[r][1].x, wv[4], s); s = fmaf(xc[r][1].y, wv[5], s);
                s = fmaf(xc[r][1].z, wv[6], s); s = fmaf(xc[r][1].w, wv[7], s);
                av[r] = s;
            }
            acc[tl] = av;
        }

        // streamed tiles with double-buffered prefetch
        MFMA16(acc[0], wA); LOADW(wA, whf, 4);
        MFMA16(acc[1], wB); LOADW(wB, whf, 5);
        MFMA16(acc[4], wA); LOADW(wA, whf, 6);
        MFMA16(acc[5], wB); LOADW(wB, whf, 7);
        MFMA16(acc[6], wA);
        MFMA16(acc[7], wB);
        // LDS-resident tiles (gate f)
        #pragma unroll
        for (int tl = 2; tl < 4; ++tl) {
            int slot = w * 2 + (tl - 2);
            f32x4 av = acc[tl];
            #pragma unroll
            for (int kc = 0; kc < 8; ++kc) {
                short8v b = ldsW[(slot * 8 + kc) * 64 + ln];
                av = __builtin_amdgcn_mfma_f32_16x16x32_bf16(ahi[kc], b, av, 0, 0, 0);
                av = __builtin_amdgcn_mfma_f32_16x16x32_bf16(alo[kc], b, av, 0, 0, 0);
            }
            acc[tl] = av;
        }

        // gate math + split-h write
        #pragma unroll
        for (int p = 0; p < 2; ++p)
            #pragma unroll
            for (int r = 0; r < 4; ++r) {
                float cc = sigf(acc[2 + p][r]) * c[p * 4 + r] + sigf(acc[p][r]) * tanh_(acc[4 + p][r]);
                c[p * 4 + r] = cc;
                float hh = sigf(acc[6 + p][r]) * tanh_(cc);
                unsigned short hi = f2bf(hh);
                float lo = hh - bf2f(hi);
                int ad = hwo + (2 * p + (col >> 3)) * 128 + (4 * q + r) * 8 + (col & 7);
                hHIs[ad] = hi;
                hLOs[ad] = f2bf(lo);
            }
        __syncthreads();
    }

    // ---- decoder: 35 steps ----
    float zd0[8], bl[8];
    #pragma unroll
    for (int tl = 0; tl < 8; ++tl) {
        zd0[tl] = zdec0[ntv[tl] * 16 + col];
        bl[tl]  = blstm[ntv[tl] * 16 + col];
    }

    for (int s = 0; s < DEC; ++s) {
        short8v ahi[8], alo[8];
        #pragma unroll
        for (int kc = 0; kc < 8; ++kc) {
            ahi[kc] = ldsHI[kc * 64 + ln];
            alo[kc] = ldsLO[kc * 64 + ln];
        }
        __syncthreads();

        f32x4 acc[8];
        if (s == 0) {
            short8v wA[8], wB[8];
            LOADW(wA, whf, 0);
            LOADW(wB, whf, 1);
            #pragma unroll
            for (int tl = 0; tl < 8; ++tl) {
                f32x4 av; av[0] = zd0[tl]; av[1] = zd0[tl]; av[2] = zd0[tl]; av[3] = zd0[tl];
                acc[tl] = av;
            }
            MFMA16(acc[0], wA); LOADW(wA, whf, 4);
            MFMA16(acc[1], wB); LOADW(wB, whf, 5);
            MFMA16(acc[4], wA); LOADW(wA, whf, 6);
            MFMA16(acc[5], wB); LOADW(wB, whf, 7);
            MFMA16(acc[6], wA);
            MFMA16(acc[7], wB);
            #pragma unroll
            for (int tl = 2; tl < 4; ++tl) {
                int slot = w * 2 + (tl - 2);
                f32x4 av = acc[tl];
                #pragma unroll
                for (int kc = 0; kc < 8; ++kc) {
                    short8v b = ldsW[(slot * 8 + kc) * 64 + ln];
                    av = __builtin_amdgcn_mfma_f32_16x16x32_bf16(ahi[kc], b, av, 0, 0, 0);
                    av = __builtin_amdgcn_mfma_f32_16x16x32_bf16(alo[kc], b, av, 0, 0, 0);
                }
                acc[tl] = av;
            }
        } else {
            short8v wA[8], wB[8];
            LOADW(wA, wsf, 0);
            LOADW(wB, wsf, 1);
            #pragma unroll
            for (int tl = 0; tl < 8; ++tl) {
                f32x4 av; av[0] = bl[tl]; av[1] = bl[tl]; av[2] = bl[tl]; av[3] = bl[tl];
                acc[tl] = av;
            }
            MFMA16(acc[0], wA); LOADW(wA, wsf, 2);
            MFMA16(acc[1], wB); LOADW(wB, wsf, 3);
            MFMA16(acc[2], wA); LOADW(wA, wsf, 4);
            MFMA16(acc[3], wB); LOADW(wB, wsf, 5);
            MFMA16(acc[4], wA); LOADW(wA, wsf, 6);
            MFMA16(acc[5], wB); LOADW(wB, wsf, 7);
            MFMA16(acc[6], wA);
            MFMA16(acc[7], wB);
        }

        #pragma unroll
        for (int p = 0; p < 2; ++p)
            #pragma unroll
            for (int r = 0; r < 4; ++r) {
                float cc = sigf(acc[2 + p][r]) * c[p * 4 + r] + sigf(acc[p][r]) * tanh_(acc[4 + p][r]);
                c[p * 4 + r] = cc;
                float hh = sigf(acc[6 + p][r]) * tanh_(cc);
                unsigned short hi = f2bf(hh);
                float lo = hh - bf2f(hi);
                int ad = hwo + (2 * p + (col >> 3)) * 128 + (4 * q + r) * 8 + (col & 7);
                hHIs[ad] = hi;
                hLOs[ad] = f2bf(lo);
            }
        __syncthreads();

        // MLP head from split-h frags
        {
            int m = tid >> 5, j = (tid >> 4) & 1, uc = tid & 15;
            float p2 = 0.f;
            #pragma unroll
            for (int i = 0; i < 16; ++i) {
                int u = i * 16 + uc;
                int ad = (u >> 5) * 512 + ((u >> 3) & 3) * 128 + m * 8 + (u & 7);
                float hv = bf2f(hHIs[ad]) + bf2f(hLOs[ad]);
                p2 = fmaf(hv, sWmlp[u * 2 + j], p2);
            }
            p2 += __shfl_down(p2, 8, 16);
            p2 += __shfl_down(p2, 4, 16);
            p2 += __shfl_down(p2, 2, 16);
            p2 += __shfl_down(p2, 1, 16);
            if (uc == 0) {
                float pr = p2 + sm[j];
                out[((size_t)(g * MW + m) * DEC + s) * 2 + j] = pr * sm[2 + j] + sm[4 + j];
            }
        }
        __syncthreads();
    }
#undef LOADW
#undef MFMA16
}

// ===================== fallback (round-2, proven) =====================
__global__ void prep_weights(const float* __restrict__ Wx, const float* __restrict__ Wh,
                             __hip_bfloat16* __restrict__ wxb,
                             __hip_bfloat16* __restrict__ whb,
                             __hip_bfloat16* __restrict__ wsb) {
    int i = blockIdx.x * 256 + threadIdx.x;
    if (i < HH * H4) {
        float x = Wx[i], h = Wh[i];
        wxb[i] = __float2bfloat16(x);
        whb[i] = __float2bfloat16(h);
        wsb[i] = __float2bfloat16(x + h);
    }
}

template<bool BF16W>
__device__ __forceinline__ void matvec2(const void* __restrict__ W,
                                        const float* __restrict__ vec,
                                        int tid, float& z0, float& z1) {
    if constexpr (BF16W) {
        const uint32_t* Wp = (const uint32_t*)W;
        #pragma unroll 8
        for (int k = 0; k < HH; ++k) {
            uint32_t w = Wp[(size_t)k * (H4 / 2) + tid];
            float s = vec[k];
            union { uint32_t u; float f; } lo, hi;
            lo.u = w << 16;
            hi.u = w & 0xffff0000u;
            z0 = fmaf(s, lo.f, z0);
            z1 = fmaf(s, hi.f, z1);
        }
    } else {
        const float2* Wp = (const float2*)W;
        #pragma unroll 8
        for (int k = 0; k < HH; ++k) {
            float2 w = Wp[(size_t)k * (H4 / 2) + tid];
            float s = vec[k];
            z0 = fmaf(s, w.x, z0);
            z1 = fmaf(s, w.y, z1);
        }
    }
}

__device__ __forceinline__ float sigmoidf_(float x) { return 1.0f / (1.0f + expf(-x)); }

template<bool BF16W>
__global__ __launch_bounds__(512)
void lstm_persist(const float* __restrict__ pulse,
                  const float* __restrict__ bn_gamma, const float* __restrict__ bn_beta,
                  const float* __restrict__ bn_mean, const float* __restrict__ bn_var,
                  const float* __restrict__ W_pe, const float* __restrict__ b_pe,
                  const float* __restrict__ embed,
                  const float* __restrict__ W_x, const float* __restrict__ W_h,
                  const float* __restrict__ b_lstm,
                  const float* __restrict__ W_mlp, const float* __restrict__ b_mlp,
                  const float* __restrict__ scale_w, const float* __restrict__ scale_b,
                  const void* __restrict__ WxQ, const void* __restrict__ WhQ,
                  const void* __restrict__ WsQ,
                  float* __restrict__ out) {
    __shared__ float sWpe2[FF * HH];
    __shared__ float sbpe2[HH];
    __shared__ float sbl[H4];
    __shared__ float sWmlp[HH * 2];
    __shared__ float sbuf[HH];
    __shared__ float hbuf[HH];
    __shared__ float cbuf[HH];
    __shared__ float zbuf[H4];
    __shared__ float bnsc[FF], bnsh[FF];
    __shared__ float smisc[6];

    const int tid = threadIdx.x;
    const int bb  = blockIdx.x;

    if (tid < FF) {
        float s = bn_gamma[tid] * rsqrtf(bn_var[tid] + 1e-3f);
        bnsc[tid] = s;
        bnsh[tid] = bn_beta[tid] - bn_mean[tid] * s;
    }
    if (tid < 2) {
        smisc[tid]     = b_mlp[tid];
        smisc[2 + tid] = scale_w[tid];
        smisc[4 + tid] = scale_b[tid];
    }
    for (int i = tid; i < H4; i += 512) sbl[i] = b_lstm[i];
    for (int i = tid; i < 2 * HH; i += 512) sWmlp[i] = W_mlp[i];
    for (int i = tid; i < HH; i += 512) { hbuf[i] = 0.f; cbuf[i] = 0.f; }
    __syncthreads();
    for (int i = tid; i < FF * HH; i += 512) sWpe2[i] = W_pe[i] * bnsc[i / HH];
    for (int i = tid; i < HH; i += 512) {
        float a = b_pe[i];
        #pragma unroll
        for (int f = 0; f < FF; ++f) a = fmaf(bnsh[f], W_pe[f * HH + i], a);
        sbpe2[i] = a;
    }
    __syncthreads();
    if (tid >= HH && tid < 2 * HH) {
        int u = tid - HH;
        const float* pr = pulse + (size_t)bb * TT * FF;
        float acc = sbpe2[u];
        #pragma unroll
        for (int f = 0; f < FF; ++f) acc = fmaf(pr[f], sWpe2[f * HH + u], acc);
        sbuf[u] = acc;
    }
    __syncthreads();

    for (int t = 0; t < TT; ++t) {
        float z0 = sbl[2 * tid], z1 = sbl[2 * tid + 1];
        if constexpr (BF16W) {
            matvec2<true>(WxQ, sbuf, tid, z0, z1);
            matvec2<true>(WhQ, hbuf, tid, z0, z1);
        } else {
            matvec2<false>(W_x, sbuf, tid, z0, z1);
            matvec2<false>(W_h, hbuf, tid, z0, z1);
        }
        zbuf[2 * tid] = z0; zbuf[2 * tid + 1] = z1;
        __syncthreads();
        if (tid < HH) {
            float iv = zbuf[tid], fv = zbuf[tid + HH];
            float gv = zbuf[tid + 2 * HH], ov = zbuf[tid + 3 * HH];
            float c = sigmoidf_(fv) * cbuf[tid] + sigmoidf_(iv) * tanhf(gv);
            cbuf[tid] = c;
            hbuf[tid] = sigmoidf_(ov) * tanhf(c);
        } else if (tid < 2 * HH) {
            int u = tid - HH;
            float acc;
            if (t + 1 < TT) {
                const float* pr = pulse + ((size_t)bb * TT + (t + 1)) * FF;
                acc = sbpe2[u];
                #pragma unroll
                for (int f = 0; f < FF; ++f) acc = fmaf(pr[f], sWpe2[f * HH + u], acc);
            } else {
                acc = embed[u];
            }
            sbuf[u] = acc;
        }
        __syncthreads();
    }

    for (int s = 0; s < DEC; ++s) {
        float z0 = sbl[2 * tid], z1 = sbl[2 * tid + 1];
        if (s == 0) {
            if constexpr (BF16W) {
                matvec2<true>(WxQ, sbuf, tid, z0, z1);
                matvec2<true>(WhQ, hbuf, tid, z0, z1);
            } else {
                matvec2<false>(W_x, sbuf, tid, z0, z1);
                matvec2<false>(W_h, hbuf, tid, z0, z1);
            }
        } else {
            if constexpr (BF16W) {
                matvec2<true>(WsQ, hbuf, tid, z0, z1);
            } else {
                matvec2<false>(W_x, hbuf, tid, z0, z1);
                matvec2<false>(W_h, hbuf, tid, z0, z1);
            }
        }
        zbuf[2 * tid] = z0; zbuf[2 * tid + 1] = z1;
        __syncthreads();
        if (tid < HH) {
            float iv = zbuf[tid], fv = zbuf[tid + HH];
            float gv = zbuf[tid + 2 * HH], ov = zbuf[tid + 3 * HH];
            float c = sigmoidf_(fv) * cbuf[tid] + sigmoidf_(iv) * tanhf(gv);
            cbuf[tid] = c;
            hbuf[tid] = sigmoidf_(ov) * tanhf(c);
        }
        __syncthreads();
        if (tid < 128) {
            int j = tid >> 6, lane = tid & 63;
            float p = 0.f;
            #pragma unroll
            for (int u = lane; u < HH; u += 64) p = fmaf(hbuf[u], sWmlp[u * 2 + j], p);
            p += __shfl_down(p, 32); p += __shfl_down(p, 16); p += __shfl_down(p, 8);
            p += __shfl_down(p, 4);  p += __shfl_down(p, 2);  p += __shfl_down(p, 1);
            if (lane == 0) {
                float pr2 = p + smisc[j];
                out[((size_t)bb * DEC + s) * 2 + j] = pr2 * smisc[2 + j] + smisc[4 + j];
            }
        }
        __syncthreads();
    }
}

extern "C" void kernel_launch(void* const* d_in, const int* in_sizes, int n_in,
                              void* d_out, int out_size, void* d_ws, size_t ws_size,
                              hipStream_t stream) {
    const float* pulse    = (const float*)d_in[0];
    const float* bn_gamma = (const float*)d_in[1];
    const float* bn_beta  = (const float*)d_in[2];
    const float* bn_mean  = (const float*)d_in[3];
    const float* bn_var   = (const float*)d_in[4];
    const float* W_pe     = (const float*)d_in[5];
    const float* b_pe     = (const float*)d_in[6];
    const float* embed    = (const float*)d_in[7];
    const float* W_x      = (const float*)d_in[8];
    const float* W_h      = (const float*)d_in[9];
    const float* b_lstm   = (const float*)d_in[10];
    const float* W_mlp    = (const float*)d_in[11];
    const float* b_mlp    = (const float*)d_in[12];
    const float* scale_w  = (const float*)d_in[13];
    const float* scale_b  = (const float*)d_in[14];
    float* out = (float*)d_out;

    // ws layout: whf 512K | wsf 512K | wpxh 16K | zbias 4K | zdec0 4K
    const size_t SZ_WF  = (size_t)64 * 8 * 64 * 16;     // 524288
    const size_t SZ_PXH = (size_t)H4 * FF * 2;          // 16384
    const size_t needA = 2 * SZ_WF + SZ_PXH + 2 * (size_t)H4 * 4;

    if (ws_size >= needA) {
        short8v* whf   = (short8v*)d_ws;
        short8v* wsf   = (short8v*)((char*)d_ws + SZ_WF);
        __half*  wpxh  = (__half*)((char*)d_ws + 2 * SZ_WF);
        float*   zbias = (float*)((char*)d_ws + 2 * SZ_WF + SZ_PXH);
        float*   zdec0 = zbias + H4;

        hipFuncSetAttribute((const void*)lstm_rec4,
                            hipFuncAttributeMaxDynamicSharedMemorySize, SMEM_TOT);

        prep_consts<<<4, 256, 0, stream>>>(W_pe, b_pe, embed, W_x, b_lstm,
                                           bn_gamma, bn_beta, bn_mean, bn_var,
                                           wpxh, zbias, zdec0);
        prep_wfrag<<<512, 64, 0, stream>>>(W_x, W_h, whf, wsf);
        lstm_rec4<<<NWG, 512, SMEM_TOT, stream>>>(whf, wsf, (const uint4*)wpxh, pulse,
                                                  zbias, zdec0, b_lstm,
                                                  W_mlp, b_mlp, scale_w, scale_b, out);
        return;
    }

    const size_t NW = (size_t)HH * H4;
    bool use_bf16 = ws_size >= 3 * NW * sizeof(__hip_bfloat16);
    __hip_bfloat16* wxb = (__hip_bfloat16*)d_ws;
    __hip_bfloat16* whb = wxb + NW;
    __hip_bfloat16* wsb = whb + NW;

    if (use_bf16) {
        prep_weights<<<(int)((NW + 255) / 256), 256, 0, stream>>>(W_x, W_h, wxb, whb, wsb);
        lstm_persist<true><<<BB, 512, 0, stream>>>(
            pulse, bn_gamma, bn_beta, bn_mean, bn_var, W_pe, b_pe, embed,
            W_x, W_h, b_lstm, W_mlp, b_mlp, scale_w, scale_b,
            (const void*)wxb, (const void*)whb, (const void*)wsb, out);
    } else {
        lstm_persist<false><<<BB, 512, 0, stream>>>(
            pulse, bn_gamma, bn_beta, bn_mean, bn_var, W_pe, b_pe, embed,
            W_x, W_h, b_lstm, W_mlp, b_mlp, scale_w, scale_b,
            nullptr, nullptr, nullptr, out);
    }
}

// Round 7
// 6005.423 us; speedup vs baseline: 2.2749x; 1.4701x over previous
//
#include <hip/hip_runtime.h>
#include <hip/hip_bf16.h>
#include <hip/hip_fp16.h>
#include <stdint.h>

#define BB  256
#define TT  512
#define FF  8
#define HH  256
#define H4  1024
#define DEC 35
#define NWG 16
#define MW  16

typedef __attribute__((ext_vector_type(8))) short short8v;
typedef __attribute__((ext_vector_type(4))) float f32x4;

// dynamic-LDS layout (bytes)
#define OFF_PX   0              // f16 wpx table: 1024 n * 16B = 16384
#define OFF_HHI  16384          // h hi A-frags, 2 buffers * 8192
#define OFF_HLO  32768          // h lo A-frags, 2 buffers * 8192
#define OFF_MLP  49152          // sWmlp 512 f32 = 2048
#define OFF_SM   51200          // 6 f32 + pad = 32
#define OFF_HB32 51232          // 16*257*4 = 16448 (decoder MLP staging)
#define SMEM_TOT 67680

__device__ __forceinline__ unsigned short f2bf(float x) {
    unsigned u = __float_as_uint(x);
    u += 0x7fffu + ((u >> 16) & 1u);          // RNE
    return (unsigned short)(u >> 16);
}
__device__ __forceinline__ float bf2f(unsigned s) { return __uint_as_float(s << 16); }
__device__ __forceinline__ float2 h2tof2(unsigned u) {
    __half2 h2 = *reinterpret_cast<const __half2*>(&u);
    return __half22float2(h2);
}
__device__ __forceinline__ float sigf(float x) {
    x = fminf(fmaxf(x, -30.f), 30.f);
    return 1.0f / (1.0f + __expf(-x));
}
__device__ __forceinline__ float tanh_(float x) {
    x = fminf(fmaxf(x, -15.f), 15.f);
    float e = __expf(2.0f * x);
    return (e - 1.0f) / (e + 1.0f);
}

// ===================== prep kernels =====================

__global__ void prep_consts(const float* __restrict__ W_pe, const float* __restrict__ b_pe,
                            const float* __restrict__ embed, const float* __restrict__ W_x,
                            const float* __restrict__ b_lstm,
                            const float* __restrict__ bn_gamma, const float* __restrict__ bn_beta,
                            const float* __restrict__ bn_mean, const float* __restrict__ bn_var,
                            __half* __restrict__ wpxh, float* __restrict__ zbias,
                            float* __restrict__ zdec0) {
    int n = blockIdx.x * 256 + threadIdx.x;
    float acc[FF];
    #pragma unroll
    for (int f = 0; f < FF; ++f) acc[f] = 0.f;
    float bsum = 0.f, dsum = 0.f;
    for (int m = 0; m < HH; ++m) {
        float wx = W_x[m * H4 + n];
        #pragma unroll
        for (int f = 0; f < FF; ++f) acc[f] = fmaf(W_pe[f * HH + m], wx, acc[f]);
        bsum = fmaf(b_pe[m], wx, bsum);
        dsum = fmaf(embed[m], wx, dsum);
    }
    float zb = b_lstm[n] + bsum;
    #pragma unroll
    for (int f = 0; f < FF; ++f) {
        float s  = bn_gamma[f] * rsqrtf(bn_var[f] + 1e-3f);
        float sh = bn_beta[f] - bn_mean[f] * s;
        wpxh[n * FF + f] = __float2half(s * acc[f]);
        zb = fmaf(sh, acc[f], zb);
    }
    zbias[n] = zb;
    zdec0[n] = b_lstm[n] + dsum;
}

// B-frags: frag[(nt*8+kc)*64+ln][j] = W[k = kc*32 + 8*(ln>>4) + j][nt*16 + (ln&15)]
__global__ void prep_wfrag(const float* __restrict__ W_x, const float* __restrict__ W_h,
                           short8v* __restrict__ whf, short8v* __restrict__ wsf) {
    int nt = blockIdx.x >> 3, kc = blockIdx.x & 7, ln = threadIdx.x;
    int n = nt * 16 + (ln & 15), q = ln >> 4;
    short8v vh, vs;
    #pragma unroll
    for (int j = 0; j < 8; ++j) {
        int k = kc * 32 + q * 8 + j;
        float wh = W_h[k * H4 + n], wx = W_x[k * H4 + n];
        vh[j] = (short)f2bf(wh);
        vs[j] = (short)f2bf(wx + wh);
    }
    whf[blockIdx.x * 64 + ln] = vh;
    wsf[blockIdx.x * 64 + ln] = vs;
}

// ===================== main recurrent kernel =====================
// 16 WGs x 512 thr, batch-group of 16 per WG. Wave w owns col-tiles
// nt = (tl>>1)*16 + 2w + (tl&1)  (all 4 gates of units [32w,32w+32)).
// K-loop is OUTER-kc / INNER-tile: per kc-slice read A-frags once (8 regs
// transient) and stream a 16B B-slice per tile (ws0/ws1 double buffer,
// 64 regs). Peak live ~110 arch VGPRs -> no spills (round 5/6 spilled:
// WRITE_SIZE 12-18MB at VGPR cap 128; this kernel's natural need fits).
// h kept SPLIT bf16 (hi+lo) in double-buffered LDS frags; zx scalar fp32.
__global__ __launch_bounds__(512) void lstm_rec5(
    const short8v* __restrict__ whf, const short8v* __restrict__ wsf,
    const uint4* __restrict__ wpx4,
    const float* __restrict__ pulse,
    const float* __restrict__ zbias, const float* __restrict__ zdec0,
    const float* __restrict__ blstm,
    const float* __restrict__ W_mlp, const float* __restrict__ b_mlp,
    const float* __restrict__ scale_w, const float* __restrict__ scale_b,
    float* __restrict__ out) {
    extern __shared__ char smem[];
    uint4*   ldsPX = (uint4*)(smem + OFF_PX);
    short8v* ldsHI = (short8v*)(smem + OFF_HHI);   // [buf][kc][ln] : buf*512 + kc*64 + ln
    short8v* ldsLO = (short8v*)(smem + OFF_HLO);
    float*   sWmlp = (float*)(smem + OFF_MLP);
    float*   sm    = (float*)(smem + OFF_SM);
    float*   hb32  = (float*)(smem + OFF_HB32);

    const int tid = threadIdx.x, g = blockIdx.x;
    const int w = tid >> 6, ln = tid & 63;
    const int col = ln & 15, q = ln >> 4;

    int ntv[8];
    #pragma unroll
    for (int tl = 0; tl < 8; ++tl) ntv[tl] = (tl >> 1) * 16 + 2 * w + (tl & 1);

    // ---- init: wpx table + zero h buffers + consts ----
    for (int i = tid; i < 1024; i += 512) ldsPX[i] = wpx4[i];
    {
        short8v zz = {};
        for (int i = tid; i < 2 * 512; i += 512) { ldsHI[i] = zz; ldsLO[i] = zz; }
    }
    for (int i = tid; i < HH * 2; i += 512) sWmlp[i] = W_mlp[i];
    if (tid < 2) { sm[tid] = b_mlp[tid]; sm[2 + tid] = scale_w[tid]; sm[4 + tid] = scale_b[tid]; }

    float zb[8];
    #pragma unroll
    for (int tl = 0; tl < 8; ++tl) zb[tl] = zbias[ntv[tl] * 16 + col];

    float c[8];
    #pragma unroll
    for (int i = 0; i < 8; ++i) c[i] = 0.f;

    const float* pbase = pulse + (size_t)(g * MW) * TT * FF;
    int rb = 0;
    __syncthreads();

    // outer-kc / inner-tile MFMA chain over one weight source (double-buffered
    // 16B-per-tile slices; compiler inserts vmcnt between load and use)
#define CHAIN8(SRC) do {                                                        \
        short8v ws0[8], ws1[8];                                                 \
        _Pragma("unroll")                                                       \
        for (int tl = 0; tl < 8; ++tl) ws0[tl] = (SRC)[(size_t)(ntv[tl] * 8 + 0) * 64 + ln]; \
        _Pragma("unroll")                                                       \
        for (int tl = 0; tl < 8; ++tl) ws1[tl] = (SRC)[(size_t)(ntv[tl] * 8 + 1) * 64 + ln]; \
        _Pragma("unroll")                                                       \
        for (int kc = 0; kc < 8; ++kc) {                                        \
            short8v ah = ldsHI[rb * 512 + kc * 64 + ln];                        \
            short8v al = ldsLO[rb * 512 + kc * 64 + ln];                        \
            if ((kc & 1) == 0) {                                                \
                _Pragma("unroll")                                               \
                for (int tl = 0; tl < 8; ++tl) {                                \
                    acc[tl] = __builtin_amdgcn_mfma_f32_16x16x32_bf16(ah, ws0[tl], acc[tl], 0, 0, 0); \
                    acc[tl] = __builtin_amdgcn_mfma_f32_16x16x32_bf16(al, ws0[tl], acc[tl], 0, 0, 0); \
                }                                                               \
                if (kc + 2 < 8) {                                               \
                    _Pragma("unroll")                                           \
                    for (int tl = 0; tl < 8; ++tl) ws0[tl] = (SRC)[(size_t)(ntv[tl] * 8 + kc + 2) * 64 + ln]; \
                }                                                               \
            } else {                                                            \
                _Pragma("unroll")                                               \
                for (int tl = 0; tl < 8; ++tl) {                                \
                    acc[tl] = __builtin_amdgcn_mfma_f32_16x16x32_bf16(ah, ws1[tl], acc[tl], 0, 0, 0); \
                    acc[tl] = __builtin_amdgcn_mfma_f32_16x16x32_bf16(al, ws1[tl], acc[tl], 0, 0, 0); \
                }                                                               \
                if (kc + 2 < 8) {                                               \
                    _Pragma("unroll")                                           \
                    for (int tl = 0; tl < 8; ++tl) ws1[tl] = (SRC)[(size_t)(ntv[tl] * 8 + kc + 2) * 64 + ln]; \
                }                                                               \
            }                                                                   \
        }                                                                       \
    } while (0)

#define GATES_WRITE(WITH_HB32) do {                                             \
        unsigned short* hHIs = (unsigned short*)(smem + OFF_HHI) + (rb ^ 1) * 4096; \
        unsigned short* hLOs = (unsigned short*)(smem + OFF_HLO) + (rb ^ 1) * 4096; \
        _Pragma("unroll")                                                       \
        for (int p = 0; p < 2; ++p)                                             \
            _Pragma("unroll")                                                   \
            for (int r = 0; r < 4; ++r) {                                       \
                float cc = sigf(acc[2 + p][r]) * c[p * 4 + r] + sigf(acc[p][r]) * tanh_(acc[4 + p][r]); \
                c[p * 4 + r] = cc;                                              \
                float hh = sigf(acc[6 + p][r]) * tanh_(cc);                     \
                unsigned short hi = f2bf(hh);                                   \
                float lo = hh - bf2f(hi);                                       \
                int ad = w * 512 + (2 * p + (col >> 3)) * 128 + (4 * q + r) * 8 + (col & 7); \
                hHIs[ad] = hi;                                                  \
                hLOs[ad] = f2bf(lo);                                            \
                if (WITH_HB32) hb32[(4 * q + r) * 257 + (32 * w + 16 * p + col)] = hh; \
            }                                                                   \
    } while (0)

    // ---- encoder: 512 steps, ONE barrier each ----
    for (int t = 0; t < TT; ++t) {
        // this step's pulse rows (L1/L2-hot; 16 lanes share each row)
        float4 xc[4][2];
        #pragma unroll
        for (int r = 0; r < 4; ++r) {
            const float* pr = pbase + (size_t)(4 * q + r) * TT * FF + (size_t)t * FF;
            xc[r][0] = ((const float4*)pr)[0];
            xc[r][1] = ((const float4*)pr)[1];
        }
        // zx init: fp32 scalar, f16 wpx from LDS
        f32x4 acc[8];
        #pragma unroll
        for (int tl = 0; tl < 8; ++tl) {
            uint4 wp = ldsPX[ntv[tl] * 16 + col];
            float wv[8];
            float2 d;
            d = h2tof2(wp.x); wv[0] = d.x; wv[1] = d.y;
            d = h2tof2(wp.y); wv[2] = d.x; wv[3] = d.y;
            d = h2tof2(wp.z); wv[4] = d.x; wv[5] = d.y;
            d = h2tof2(wp.w); wv[6] = d.x; wv[7] = d.y;
            f32x4 av;
            #pragma unroll
            for (int r = 0; r < 4; ++r) {
                float s = zb[tl];
                s = fmaf(xc[r][0].x, wv[0], s); s = fmaf(xc[r][0].y, wv[1], s);
                s = fmaf(xc[r][0].z, wv[2], s); s = fmaf(xc[r][0].w, wv[3], s);
                s = fmaf(xc[r][1].x, wv[4], s); s = fmaf(xc[r][1].y, wv[5], s);
                s = fmaf(xc[r][1].z, wv[6], s); s = fmaf(xc[r][1].w, wv[7], s);
                av[r] = s;
            }
            acc[tl] = av;
        }
        CHAIN8(whf);
        GATES_WRITE(0);
        __syncthreads();
        rb ^= 1;
    }

    // ---- decoder: 35 steps ----
    float zd0[8], bl[8];
    #pragma unroll
    for (int tl = 0; tl < 8; ++tl) {
        zd0[tl] = zdec0[ntv[tl] * 16 + col];
        bl[tl]  = blstm[ntv[tl] * 16 + col];
    }

    for (int s = 0; s < DEC; ++s) {
        f32x4 acc[8];
        if (s == 0) {
            #pragma unroll
            for (int tl = 0; tl < 8; ++tl) {
                f32x4 av; av[0] = zd0[tl]; av[1] = zd0[tl]; av[2] = zd0[tl]; av[3] = zd0[tl];
                acc[tl] = av;
            }
            CHAIN8(whf);
        } else {
            #pragma unroll
            for (int tl = 0; tl < 8; ++tl) {
                f32x4 av; av[0] = bl[tl]; av[1] = bl[tl]; av[2] = bl[tl]; av[3] = bl[tl];
                acc[tl] = av;
            }
            CHAIN8(wsf);
        }
        GATES_WRITE(1);
        __syncthreads();

        // MLP head: pred = h@W_mlp + b_mlp; eis = pred*sw + sb
        {
            int m = tid >> 5, j = (tid >> 4) & 1, uc = tid & 15;
            float p2 = 0.f;
            #pragma unroll
            for (int i = 0; i < 16; ++i) {
                int u = i * 16 + uc;
                p2 = fmaf(hb32[m * 257 + u], sWmlp[u * 2 + j], p2);
            }
            p2 += __shfl_down(p2, 8, 16);
            p2 += __shfl_down(p2, 4, 16);
            p2 += __shfl_down(p2, 2, 16);
            p2 += __shfl_down(p2, 1, 16);
            if (uc == 0) {
                float pr = p2 + sm[j];
                out[((size_t)(g * MW + m) * DEC + s) * 2 + j] = pr * sm[2 + j] + sm[4 + j];
            }
        }
        __syncthreads();
        rb ^= 1;
    }
#undef CHAIN8
#undef GATES_WRITE
}

// ===================== fallback (round-2, proven) =====================
__global__ void prep_weights(const float* __restrict__ Wx, const float* __restrict__ Wh,
                             __hip_bfloat16* __restrict__ wxb,
                             __hip_bfloat16* __restrict__ whb,
                             __hip_bfloat16* __restrict__ wsb) {
    int i = blockIdx.x * 256 + threadIdx.x;
    if (i < HH * H4) {
        float x = Wx[i], h = Wh[i];
        wxb[i] = __float2bfloat16(x);
        whb[i] = __float2bfloat16(h);
        wsb[i] = __float2bfloat16(x + h);
    }
}

template<bool BF16W>
__device__ __forceinline__ void matvec2(const void* __restrict__ W,
                                        const float* __restrict__ vec,
                                        int tid, float& z0, float& z1) {
    if constexpr (BF16W) {
        const uint32_t* Wp = (const uint32_t*)W;
        #pragma unroll 8
        for (int k = 0; k < HH; ++k) {
            uint32_t w = Wp[(size_t)k * (H4 / 2) + tid];
            float s = vec[k];
            union { uint32_t u; float f; } lo, hi;
            lo.u = w << 16;
            hi.u = w & 0xffff0000u;
            z0 = fmaf(s, lo.f, z0);
            z1 = fmaf(s, hi.f, z1);
        }
    } else {
        const float2* Wp = (const float2*)W;
        #pragma unroll 8
        for (int k = 0; k < HH; ++k) {
            float2 w = Wp[(size_t)k * (H4 / 2) + tid];
            float s = vec[k];
            z0 = fmaf(s, w.x, z0);
            z1 = fmaf(s, w.y, z1);
        }
    }
}

__device__ __forceinline__ float sigmoidf_(float x) { return 1.0f / (1.0f + expf(-x)); }

template<bool BF16W>
__global__ __launch_bounds__(512)
void lstm_persist(const float* __restrict__ pulse,
                  const float* __restrict__ bn_gamma, const float* __restrict__ bn_beta,
                  const float* __restrict__ bn_mean, const float* __restrict__ bn_var,
                  const float* __restrict__ W_pe, const float* __restrict__ b_pe,
                  const float* __restrict__ embed,
                  const float* __restrict__ W_x, const float* __restrict__ W_h,
                  const float* __restrict__ b_lstm,
                  const float* __restrict__ W_mlp, const float* __restrict__ b_mlp,
                  const float* __restrict__ scale_w, const float* __restrict__ scale_b,
                  const void* __restrict__ WxQ, const void* __restrict__ WhQ,
                  const void* __restrict__ WsQ,
                  float* __restrict__ out) {
    __shared__ float sWpe2[FF * HH];
    __shared__ float sbpe2[HH];
    __shared__ float sbl[H4];
    __shared__ float sWmlp[HH * 2];
    __shared__ float sbuf[HH];
    __shared__ float hbuf[HH];
    __shared__ float cbuf[HH];
    __shared__ float zbuf[H4];
    __shared__ float bnsc[FF], bnsh[FF];
    __shared__ float smisc[6];

    const int tid = threadIdx.x;
    const int bb  = blockIdx.x;

    if (tid < FF) {
        float s = bn_gamma[tid] * rsqrtf(bn_var[tid] + 1e-3f);
        bnsc[tid] = s;
        bnsh[tid] = bn_beta[tid] - bn_mean[tid] * s;
    }
    if (tid < 2) {
        smisc[tid]     = b_mlp[tid];
        smisc[2 + tid] = scale_w[tid];
        smisc[4 + tid] = scale_b[tid];
    }
    for (int i = tid; i < H4; i += 512) sbl[i] = b_lstm[i];
    for (int i = tid; i < 2 * HH; i += 512) sWmlp[i] = W_mlp[i];
    for (int i = tid; i < HH; i += 512) { hbuf[i] = 0.f; cbuf[i] = 0.f; }
    __syncthreads();
    for (int i = tid; i < FF * HH; i += 512) sWpe2[i] = W_pe[i] * bnsc[i / HH];
    for (int i = tid; i < HH; i += 512) {
        float a = b_pe[i];
        #pragma unroll
        for (int f = 0; f < FF; ++f) a = fmaf(bnsh[f], W_pe[f * HH + i], a);
        sbpe2[i] = a;
    }
    __syncthreads();
    if (tid >= HH && tid < 2 * HH) {
        int u = tid - HH;
        const float* pr = pulse + (size_t)bb * TT * FF;
        float acc = sbpe2[u];
        #pragma unroll
        for (int f = 0; f < FF; ++f) acc = fmaf(pr[f], sWpe2[f * HH + u], acc);
        sbuf[u] = acc;
    }
    __syncthreads();

    for (int t = 0; t < TT; ++t) {
        float z0 = sbl[2 * tid], z1 = sbl[2 * tid + 1];
        if constexpr (BF16W) {
            matvec2<true>(WxQ, sbuf, tid, z0, z1);
            matvec2<true>(WhQ, hbuf, tid, z0, z1);
        } else {
            matvec2<false>(W_x, sbuf, tid, z0, z1);
            matvec2<false>(W_h, hbuf, tid, z0, z1);
        }
        zbuf[2 * tid] = z0; zbuf[2 * tid + 1] = z1;
        __syncthreads();
        if (tid < HH) {
            float iv = zbuf[tid], fv = zbuf[tid + HH];
            float gv = zbuf[tid + 2 * HH], ov = zbuf[tid + 3 * HH];
            float c = sigmoidf_(fv) * cbuf[tid] + sigmoidf_(iv) * tanhf(gv);
            cbuf[tid] = c;
            hbuf[tid] = sigmoidf_(ov) * tanhf(c);
        } else if (tid < 2 * HH) {
            int u = tid - HH;
            float acc;
            if (t + 1 < TT) {
                const float* pr = pulse + ((size_t)bb * TT + (t + 1)) * FF;
                acc = sbpe2[u];
                #pragma unroll
                for (int f = 0; f < FF; ++f) acc = fmaf(pr[f], sWpe2[f * HH + u], acc);
            } else {
                acc = embed[u];
            }
            sbuf[u] = acc;
        }
        __syncthreads();
    }

    for (int s = 0; s < DEC; ++s) {
        float z0 = sbl[2 * tid], z1 = sbl[2 * tid + 1];
        if (s == 0) {
            if constexpr (BF16W) {
                matvec2<true>(WxQ, sbuf, tid, z0, z1);
                matvec2<true>(WhQ, hbuf, tid, z0, z1);
            } else {
                matvec2<false>(W_x, sbuf, tid, z0, z1);
                matvec2<false>(W_h, hbuf, tid, z0, z1);
            }
        } else {
            if constexpr (BF16W) {
                matvec2<true>(WsQ, hbuf, tid, z0, z1);
            } else {
                matvec2<false>(W_x, hbuf, tid, z0, z1);
                matvec2<false>(W_h, hbuf, tid, z0, z1);
            }
        }
        zbuf[2 * tid] = z0; zbuf[2 * tid + 1] = z1;
        __syncthreads();
        if (tid < HH) {
            float iv = zbuf[tid], fv = zbuf[tid + HH];
            float gv = zbuf[tid + 2 * HH], ov = zbuf[tid + 3 * HH];
            float c = sigmoidf_(fv) * cbuf[tid] + sigmoidf_(iv) * tanhf(gv);
            cbuf[tid] = c;
            hbuf[tid] = sigmoidf_(ov) * tanhf(c);
        }
        __syncthreads();
        if (tid < 128) {
            int j = tid >> 6, lane = tid & 63;
            float p = 0.f;
            #pragma unroll
            for (int u = lane; u < HH; u += 64) p = fmaf(hbuf[u], sWmlp[u * 2 + j], p);
            p += __shfl_down(p, 32); p += __shfl_down(p, 16); p += __shfl_down(p, 8);
            p += __shfl_down(p, 4);  p += __shfl_down(p, 2);  p += __shfl_down(p, 1);
            if (lane == 0) {
                float pr2 = p + smisc[j];
                out[((size_t)bb * DEC + s) * 2 + j] = pr2 * smisc[2 + j] + smisc[4 + j];
            }
        }
        __syncthreads();
    }
}

extern "C" void kernel_launch(void* const* d_in, const int* in_sizes, int n_in,
                              void* d_out, int out_size, void* d_ws, size_t ws_size,
                              hipStream_t stream) {
    const float* pulse    = (const float*)d_in[0];
    const float* bn_gamma = (const float*)d_in[1];
    const float* bn_beta  = (const float*)d_in[2];
    const float* bn_mean  = (const float*)d_in[3];
    const float* bn_var   = (const float*)d_in[4];
    const float* W_pe     = (const float*)d_in[5];
    const float* b_pe     = (const float*)d_in[6];
    const float* embed    = (const float*)d_in[7];
    const float* W_x      = (const float*)d_in[8];
    const float* W_h      = (const float*)d_in[9];
    const float* b_lstm   = (const float*)d_in[10];
    const float* W_mlp    = (const float*)d_in[11];
    const float* b_mlp    = (const float*)d_in[12];
    const float* scale_w  = (const float*)d_in[13];
    const float* scale_b  = (const float*)d_in[14];
    float* out = (float*)d_out;

    // ws layout: whf 512K | wsf 512K | wpxh 16K | zbias 4K | zdec0 4K
    const size_t SZ_WF  = (size_t)64 * 8 * 64 * 16;     // 524288
    const size_t SZ_PXH = (size_t)H4 * FF * 2;          // 16384
    const size_t needA = 2 * SZ_WF + SZ_PXH + 2 * (size_t)H4 * 4;

    if (ws_size >= needA) {
        short8v* whf   = (short8v*)d_ws;
        short8v* wsf   = (short8v*)((char*)d_ws + SZ_WF);
        __half*  wpxh  = (__half*)((char*)d_ws + 2 * SZ_WF);
        float*   zbias = (float*)((char*)d_ws + 2 * SZ_WF + SZ_PXH);
        float*   zdec0 = zbias + H4;

        hipFuncSetAttribute((const void*)lstm_rec5,
                            hipFuncAttributeMaxDynamicSharedMemorySize, SMEM_TOT);

        prep_consts<<<4, 256, 0, stream>>>(W_pe, b_pe, embed, W_x, b_lstm,
                                           bn_gamma, bn_beta, bn_mean, bn_var,
                                           wpxh, zbias, zdec0);
        prep_wfrag<<<512, 64, 0, stream>>>(W_x, W_h, whf, wsf);
        lstm_rec5<<<NWG, 512, SMEM_TOT, stream>>>(whf, wsf, (const uint4*)wpxh, pulse,
                                                  zbias, zdec0, b_lstm,
                                                  W_mlp, b_mlp, scale_w, scale_b, out);
        return;
    }

    const size_t NW = (size_t)HH * H4;
    bool use_bf16 = ws_size >= 3 * NW * sizeof(__hip_bfloat16);
    __hip_bfloat16* wxb = (__hip_bfloat16*)d_ws;
    __hip_bfloat16* whb = wxb + NW;
    __hip_bfloat16* wsb = whb + NW;

    if (use_bf16) {
        prep_weights<<<(int)((NW + 255) / 256), 256, 0, stream>>>(W_x, W_h, wxb, whb, wsb);
        lstm_persist<true><<<BB, 512, 0, stream>>>(
            pulse, bn_gamma, bn_beta, bn_mean, bn_var, W_pe, b_pe, embed,
            W_x, W_h, b_lstm, W_mlp, b_mlp, scale_w, scale_b,
            (const void*)wxb, (const void*)whb, (const void*)wsb, out);
    } else {
        lstm_persist<false><<<BB, 512, 0, stream>>>(
            pulse, bn_gamma, bn_beta, bn_mean, bn_var, W_pe, b_pe, embed,
            W_x, W_h, b_lstm, W_mlp, b_mlp, scale_w, scale_b,
            nullptr, nullptr, nullptr, out);
    }
}